// Round 12
// baseline (266.938 us; speedup 1.0000x reference)
//
#include <hip/hip_runtime.h>
#include <hip/hip_bf16.h>

#define NU 50000
#define NI 30000
#define NN 80000     // NU + NI
#define KDIM 64
#define DD0 768
#define DD1 128
#define DD 896       // DD0 + DD1

#define BROWS 128            // dst rows per bucket
#define NB (NN / BROWS)      // 625 buckets
#define CAPB 5120            // entries per bucket region
#define CAP 96               // uniform ELL capacity per row (u16 slots)
#define REGION_BYTES 24576   // per-bucket region
#define ENTS_STRIDE (REGION_BYTES / 4)
#define CHUNK_PAIRS 4096

typedef __attribute__((ext_vector_type(8))) short short8v;
typedef __attribute__((ext_vector_type(4))) short short4v;
typedef __attribute__((ext_vector_type(4))) float float4v;
typedef unsigned short ushort_t;

struct bf16pair { short hi, lo; };

__device__ inline bf16pair f32_split_bf16(float v) {
    __hip_bfloat16 h = __float2bfloat16(v);
    float hf = __bfloat162float(h);
    __hip_bfloat16 l = __float2bfloat16(v - hf);
    bf16pair p;
    p.hi = *reinterpret_cast<short*>(&h);
    p.lo = *reinterpret_cast<short*>(&l);
    return p;
}

__device__ inline float bf16bits_to_f32(ushort_t u) {
    return __uint_as_float(((unsigned int)u) << 16);
}

__device__ inline ushort_t f32_to_bf16_rne(float f) {
    unsigned int u = __float_as_uint(f);
    unsigned int r = (u + 0x7FFFu + ((u >> 16) & 1u)) >> 16;
    return (ushort_t)r;
}

// ---------------------------------------------------------------------------
// W -> transposed bf16 hi/lo:  WTh/WTl[col][k]
// ---------------------------------------------------------------------------
__global__ void wtcvt_kernel(const float* __restrict__ W,
                             short* __restrict__ WTh, short* __restrict__ WTl)
{
    const int i = blockIdx.x * 256 + threadIdx.x;   // over DD*KDIM
    if (i < DD * KDIM) {
        const int k = i >> 6, col = i & 63;
        const bf16pair p = f32_split_bf16(W[i]);
        WTh[col * DD + k] = p.hi;
        WTl[col * DD + k] = p.lo;
    }
}

// ---------------------------------------------------------------------------
// 1) proj, LDS-free: F_proj = l2norm(concat(F0,F1) @ W + b).
// Block = 128 thr = 2 waves = one 16-row tile x two 32-col halves.
// A-fragments loaded straight from global F (lane: 2xfloat4 contiguous),
// converted in-register to bf16 hi/lo. B-fragments from L2-resident WTh/WTl.
// No staging LDS, no k-loop barriers; one tiny barrier for cross-half L2-norm.
// Writes f32 item rows into Fp, bf16 dinv-scaled rows into curS.
// ---------------------------------------------------------------------------
__global__ __launch_bounds__(128) void proj_kernel(
    const float* __restrict__ F0, const float* __restrict__ F1,
    const short* __restrict__ WTh, const short* __restrict__ WTl,
    const float* __restrict__ b, const float* __restrict__ dinv,
    float* __restrict__ Fp, ushort_t* __restrict__ curS)
{
    __shared__ float ssL[2][16];

    const int tid  = threadIdx.x;
    const int half = tid >> 6;          // wave 0/1 -> cols half*32..+31
    const int lane = tid & 63;
    const int lr   = lane & 15;         // frag row (A) / col-in-tile (B)
    const int grp  = lane >> 4;         // frag k-group (8 k each)
    const int rowBase = blockIdx.x * 16;
    const int r    = rowBase + lr;      // A row this lane serves (< NI always)
    const int colBase = half * 32;

    float4v acc[2] = {};                // 2 n-tiles of 16x16

    auto kstep = [&](const float* __restrict__ Fsrc, int stride, int kOff,
                     int kGlob) {
        const float4 fa0 = *(const float4*)&Fsrc[(size_t)r * stride + kOff + grp * 8];
        const float4 fa1 = *(const float4*)&Fsrc[(size_t)r * stride + kOff + grp * 8 + 4];
        short8v ah, al;
        {
            const bf16pair q0 = f32_split_bf16(fa0.x);
            const bf16pair q1 = f32_split_bf16(fa0.y);
            const bf16pair q2 = f32_split_bf16(fa0.z);
            const bf16pair q3 = f32_split_bf16(fa0.w);
            const bf16pair q4 = f32_split_bf16(fa1.x);
            const bf16pair q5 = f32_split_bf16(fa1.y);
            const bf16pair q6 = f32_split_bf16(fa1.z);
            const bf16pair q7 = f32_split_bf16(fa1.w);
            ah[0]=q0.hi; ah[1]=q1.hi; ah[2]=q2.hi; ah[3]=q3.hi;
            ah[4]=q4.hi; ah[5]=q5.hi; ah[6]=q6.hi; ah[7]=q7.hi;
            al[0]=q0.lo; al[1]=q1.lo; al[2]=q2.lo; al[3]=q3.lo;
            al[4]=q4.lo; al[5]=q5.lo; al[6]=q6.lo; al[7]=q7.lo;
        }
        #pragma unroll
        for (int nt = 0; nt < 2; ++nt) {
            const int bc = colBase + nt * 16 + lr;
            const short8v bh = *(const short8v*)&WTh[(size_t)bc * DD + kGlob + grp * 8];
            const short8v bl = *(const short8v*)&WTl[(size_t)bc * DD + kGlob + grp * 8];
            acc[nt] = __builtin_amdgcn_mfma_f32_16x16x32_bf16(ah, bh, acc[nt], 0, 0, 0);
            acc[nt] = __builtin_amdgcn_mfma_f32_16x16x32_bf16(ah, bl, acc[nt], 0, 0, 0);
            acc[nt] = __builtin_amdgcn_mfma_f32_16x16x32_bf16(al, bh, acc[nt], 0, 0, 0);
        }
    };

    #pragma unroll 4
    for (int c = 0; c < 24; ++c)          // F0: k = 0..767
        kstep(F0, DD0, c * 32, c * 32);
    #pragma unroll
    for (int c = 0; c < 4; ++c)           // F1: k = 768..895
        kstep(F1, DD1, c * 32, DD0 + c * 32);

    // epilogue: lane holds D[row=4*grp+i][col = colBase + nt*16 + lr]
    float bias[2];
    #pragma unroll
    for (int nt = 0; nt < 2; ++nt) bias[nt] = b[colBase + nt * 16 + lr];

    float y[2][4];
    #pragma unroll
    for (int i = 0; i < 4; ++i) {
        float s = 0.f;
        #pragma unroll
        for (int nt = 0; nt < 2; ++nt) {
            y[nt][i] = acc[nt][i] + bias[nt];
            s += y[nt][i] * y[nt][i];
        }
        s += __shfl_xor(s, 1);
        s += __shfl_xor(s, 2);
        s += __shfl_xor(s, 4);
        s += __shfl_xor(s, 8);
        if (lr == 0) ssL[half][grp * 4 + i] = s;   // per-half partial
    }
    __syncthreads();
    #pragma unroll
    for (int i = 0; i < 4; ++i) {
        const int rl = grp * 4 + i;
        const float ss = ssL[0][rl] + ssL[1][rl];
        const int rw = rowBase + rl;
        const float inv = 1.0f / fmaxf(sqrtf(ss), 1e-12f);
        const float dv  = dinv[NU + rw];
        #pragma unroll
        for (int nt = 0; nt < 2; ++nt) {
            const float o = y[nt][i] * inv;
            Fp[(size_t)(NU + rw) * KDIM + colBase + nt * 16 + lr] = o;
            curS[(size_t)(NU + rw) * KDIM + colBase + nt * 16 + lr] =
                f32_to_bf16_rne(o * dv);
        }
    }
}

// user rows: curS = bf16(Gu * dinv[row])   (x0 for users is read from Gu)
__global__ void userinit_kernel(const float* __restrict__ Gu,
                                const float* __restrict__ dinv,
                                ushort_t* __restrict__ curS)
{
    const int i = blockIdx.x * blockDim.x + threadIdx.x;  // float4 index
    if (i < NU * KDIM / 4) {
        const int row = i >> 4;
        const float dv = dinv[row];
        const float4 g = ((const float4*)Gu)[i];
        short4v s;
        s[0] = (short)f32_to_bf16_rne(g.x * dv);
        s[1] = (short)f32_to_bf16_rne(g.y * dv);
        s[2] = (short)f32_to_bf16_rne(g.z * dv);
        s[3] = (short)f32_to_bf16_rne(g.w * dv);
        *(short4v*)&curS[(size_t)i * 4] = s;
    }
}

// ---------------------------------------------------------------------------
// Partition: bucket 2M directed entries by dst>>7 (R7-proven).
// ---------------------------------------------------------------------------
__global__ __launch_bounds__(256) void part_kernel(
    const int* __restrict__ src, const int* __restrict__ dst,
    int* __restrict__ bcur, unsigned int* __restrict__ ents, int E2)
{
    __shared__ int bcntL[NB];
    __shared__ int bposL[NB];
    const int tid = threadIdx.x;
    const int pairBase = blockIdx.x * CHUNK_PAIRS;

    for (int i = tid; i < NB; i += 256) bcntL[i] = 0;
    __syncthreads();

    #pragma unroll
    for (int it = 0; it < CHUNK_PAIRS / 256; ++it) {
        const int p = pairBase + it * 256 + tid;
        if (p < E2) {
            const int u  = src[p];
            const int iF = dst[p];
            atomicAdd(&bcntL[iF >> 7], 1);
            atomicAdd(&bcntL[u  >> 7], 1);
        }
    }
    __syncthreads();

    for (int bkt = tid; bkt < NB; bkt += 256) {
        const int c = bcntL[bkt];
        bposL[bkt] = (c > 0) ? atomicAdd(&bcur[bkt], c) : 0;
        bcntL[bkt] = 0;
    }
    __syncthreads();

    #pragma unroll
    for (int it = 0; it < CHUNK_PAIRS / 256; ++it) {
        const int p = pairBase + it * 256 + tid;
        if (p < E2) {
            const int u  = src[p];
            const int iF = dst[p];
            {
                const int bkt = iF >> 7;
                const int k = bposL[bkt] + atomicAdd(&bcntL[bkt], 1);
                if (k < CAPB)
                    ents[(size_t)bkt * ENTS_STRIDE + k] =
                        ((unsigned int)(iF & 127) << 16) | (unsigned int)u;
            }
            {
                const int bkt = u >> 7;
                const int k = bposL[bkt] + atomicAdd(&bcntL[bkt], 1);
                if (k < CAPB)
                    ents[(size_t)bkt * ENTS_STRIDE + k] =
                        ((unsigned int)(u & 127) << 16) | (unsigned int)(iF - NU);
            }
        }
    }
}

// ---------------------------------------------------------------------------
// toELL: stage bucket entries in LDS, place into u16 ELL [row][CAP]; emits
// cnt + dinv. (ELL aliases the entry region; LDS staging makes that safe.)
// ---------------------------------------------------------------------------
__global__ __launch_bounds__(256) void toELL_kernel(
    const int* __restrict__ bcur, unsigned int* __restrict__ ents,
    ushort_t* __restrict__ col,
    int* __restrict__ cnt, float* __restrict__ dinv)
{
    __shared__ unsigned int eL[CAPB];
    __shared__ int curL[BROWS];
    const int bkt = blockIdx.x;
    const int tid = threadIdx.x;

    int n = bcur[bkt]; n = (n < CAPB) ? n : CAPB;
    const unsigned int* ep = ents + (size_t)bkt * ENTS_STRIDE;

    for (int j = tid; j < n; j += 256) eL[j] = ep[j];
    if (tid < BROWS) curL[tid] = 0;
    __syncthreads();

    const size_t rowB = (size_t)bkt * BROWS;
    for (int j = tid; j < n; j += 256) {
        const unsigned int e = eL[j];
        const int dl = (int)(e >> 16);
        const int slot = atomicAdd(&curL[dl], 1);
        if (slot < CAP)
            col[(rowB + dl) * CAP + slot] = (ushort_t)(e & 0xFFFFu);
    }
    __syncthreads();

    if (tid < BROWS) {
        int c = curL[tid];
        c = (c < CAP) ? c : CAP;
        const size_t row = rowB + tid;
        cnt[row]  = c;
        dinv[row] = (c > 0) ? rsqrtf((float)c) : 0.0f;
    }
}

// ---------------------------------------------------------------------------
// 3) pull: nxtS[row] = bf16( dinv[row]^2 * sum_j curS[col_j] ).
// Phase-split by dst side for gather L2 locality.
// ---------------------------------------------------------------------------
__global__ __launch_bounds__(256) void pull_kernel(
    const ushort_t* __restrict__ curS, ushort_t* __restrict__ nxtS,
    const int* __restrict__ cnt,
    const ushort_t* __restrict__ col,
    const float* __restrict__ dinv,
    int rowStart, int nRows)
{
    const int wid  = (blockIdx.x * blockDim.x + threadIdx.x) >> 6;
    const int lane = threadIdx.x & 63;
    if (wid >= nRows) return;
    const int row = rowStart + wid;

    const ushort_t* cp = col + (size_t)row * CAP;
    const int addB = (row < NU) ? NU : 0;
    const int n = cnt[row];

    float a0 = 0.0f, a1 = 0.0f;
    int j = 0;
    for (; j + 8 <= n; j += 8) {
        int s[8];
        #pragma unroll
        for (int q = 0; q < 8; ++q) s[q] = (int)cp[j + q] + addB;
        float v[8];
        #pragma unroll
        for (int q = 0; q < 8; ++q)
            v[q] = bf16bits_to_f32(curS[(size_t)s[q] * KDIM + lane]);
        a0 += v[0] + v[2] + v[4] + v[6];
        a1 += v[1] + v[3] + v[5] + v[7];
    }
    for (; j < n; ++j)
        a0 += bf16bits_to_f32(curS[(size_t)((int)cp[j] + addB) * KDIM + lane]);

    const float dv = dinv[row];
    nxtS[(size_t)row * KDIM + lane] = f32_to_bf16_rne(dv * dv * (a0 + a1));
}

// ---------------------------------------------------------------------------
// 4) out: acc_r = x0_r + (S1_r + S2_r)/dinv_r + dinv_r * sum_j S2[col_j(r)]
//    xui[b] = (1/16) * dot(acc_u, acc_i).  Layer-3 evaluated only here.
// ---------------------------------------------------------------------------
__device__ inline float row_acc(int row, float x0, int lane,
                                const ushort_t* __restrict__ S1,
                                const ushort_t* __restrict__ S2,
                                const int* __restrict__ cnt,
                                const ushort_t* __restrict__ col,
                                const float* __restrict__ dinv)
{
    const float dv  = dinv[row];
    const float rdv = (dv > 0.f) ? 1.0f / dv : 0.0f;
    const float s1 = bf16bits_to_f32(S1[(size_t)row * KDIM + lane]);
    const float s2 = bf16bits_to_f32(S2[(size_t)row * KDIM + lane]);

    const ushort_t* cp = col + (size_t)row * CAP;
    const int addB = (row < NU) ? NU : 0;
    const int n = cnt[row];
    float a0 = 0.0f, a1 = 0.0f;
    int j = 0;
    for (; j + 8 <= n; j += 8) {
        int s[8];
        #pragma unroll
        for (int q = 0; q < 8; ++q) s[q] = (int)cp[j + q] + addB;
        float v[8];
        #pragma unroll
        for (int q = 0; q < 8; ++q)
            v[q] = bf16bits_to_f32(S2[(size_t)s[q] * KDIM + lane]);
        a0 += v[0] + v[2] + v[4] + v[6];
        a1 += v[1] + v[3] + v[5] + v[7];
    }
    for (; j < n; ++j)
        a0 += bf16bits_to_f32(S2[(size_t)((int)cp[j] + addB) * KDIM + lane]);

    return x0 + (s1 + s2) * rdv + dv * (a0 + a1);
}

__global__ __launch_bounds__(256) void out_kernel(
    const float* __restrict__ Gu, const float* __restrict__ Fp,
    const ushort_t* __restrict__ S1, const ushort_t* __restrict__ S2,
    const int* __restrict__ cnt, const ushort_t* __restrict__ col,
    const float* __restrict__ dinv,
    const int* __restrict__ uidx, const int* __restrict__ iidx,
    float* __restrict__ out, int B)
{
    const int wid  = (blockIdx.x * blockDim.x + threadIdx.x) >> 6;
    const int lane = threadIdx.x & 63;
    if (wid >= B) return;
    const int u  = uidx[wid];
    const int rI = NU + iidx[wid];

    const float au = row_acc(u,  Gu[(size_t)u  * KDIM + lane], lane,
                             S1, S2, cnt, col, dinv);
    const float ai = row_acc(rI, Fp[(size_t)rI * KDIM + lane], lane,
                             S1, S2, cnt, col, dinv);
    float p = au * ai;
    #pragma unroll
    for (int m = 32; m >= 1; m >>= 1) p += __shfl_xor(p, m);
    if (lane == 0) out[wid] = p * (1.0f / 16.0f);
}

extern "C" void kernel_launch(void* const* d_in, const int* in_sizes, int n_in,
                              void* d_out, int out_size, void* d_ws, size_t ws_size,
                              hipStream_t stream)
{
    const float* Gu = (const float*)d_in[0];
    const float* F0 = (const float*)d_in[1];
    const float* F1 = (const float*)d_in[2];
    const float* W  = (const float*)d_in[3];
    const float* pb = (const float*)d_in[4];
    const int* edge = (const int*)d_in[5];
    const int* uidx = (const int*)d_in[6];
    const int* iidx = (const int*)d_in[7];
    const int E  = in_sizes[5] / 2;      // 2,000,000 directed edges
    const int E2 = E / 2;                // 1,000,000 mirrored pairs
    const int B = in_sizes[6];           // 4096
    const int* srcp = edge;              // first E2: user ids
    const int* dstp = edge + E;          // first E2: item ids (+NU)

    const size_t XE = (size_t)NN * KDIM;
    float*    Fp    = (float*)d_ws;                        // XE f32 (items)
    ushort_t* curA  = (ushort_t*)(Fp + XE);                // XE bf16
    ushort_t* curB  = curA + XE;                           // XE bf16
    float*    dinv  = (float*)(curB + XE);                 // NN
    int*      cnt   = (int*)(dinv + NN);                   // NN
    int*      bcur  = cnt + NN;                            // NB
    short*    WTh   = (short*)(bcur + NB);                 // 64*896
    short*    WTl   = WTh + (size_t)KDIM * DD;             // 64*896
    ushort_t* col   = (ushort_t*)(WTl + (size_t)KDIM * DD);
    unsigned int* ents = (unsigned int*)col;               // aliased region

    // build: partition -> bucket-local ELL (emits cnt, dinv)
    (void)hipMemsetAsync(bcur, 0, NB * sizeof(int), stream);
    part_kernel<<<(E2 + CHUNK_PAIRS - 1) / CHUNK_PAIRS, 256, 0, stream>>>(
        srcp, dstp, bcur, ents, E2);
    toELL_kernel<<<NB, 256, 0, stream>>>(bcur, ents, col, cnt, dinv);

    // W -> transposed bf16 hi/lo
    wtcvt_kernel<<<(DD * KDIM + 255) / 256, 256, 0, stream>>>(W, WTh, WTl);

    // S0: curA = bf16(dinv .* x0)  (x0 = [Gu; Fproj]; Fp keeps item x0 in f32)
    userinit_kernel<<<(NU * KDIM / 4 + 255) / 256, 256, 0, stream>>>(
        Gu, dinv, curA);
    proj_kernel<<<NI / 16, 128, 0, stream>>>(F0, F1, WTh, WTl, pb,
                                             dinv, Fp, curA);

    // layers 1-2 (phase-split); S1 = curB, S2 = curA (overwrites dead S0)
    const int gridU = (NU * 64 + 255) / 256;
    const int gridI = (NI * 64 + 255) / 256;
    pull_kernel<<<gridU, 256, 0, stream>>>(curA, curB, cnt, col, dinv, 0, NU);
    pull_kernel<<<gridI, 256, 0, stream>>>(curA, curB, cnt, col, dinv, NU, NI);
    pull_kernel<<<gridU, 256, 0, stream>>>(curB, curA, cnt, col, dinv, 0, NU);
    pull_kernel<<<gridI, 256, 0, stream>>>(curB, curA, cnt, col, dinv, NU, NI);

    // out: layer-3 at sampled rows only + mean + dot
    out_kernel<<<(int)(((size_t)B * 64 + 255) / 256), 256, 0, stream>>>(
        Gu, Fp, curB, curA, cnt, col, dinv, uidx, iidx, (float*)d_out, B);
}